// Round 7
// baseline (1349.739 us; speedup 1.0000x reference)
//
#include <hip/hip_runtime.h>
#include <math.h>

// TAGConv 2-layer GNN on MI355X.
// R7: XCD-pinned column-partitioned props -- feature dim split into groups of
// 16 floats, group g pinned to XCD g (cg = blockIdx & 7); per-XCD gather
// working set 3.2MB -> L2-resident. Meta streamed nontemporally (8x re-read)
// so it can't evict the feature set. Quarter-wave layout: 4 edges in flight
// per gather instr, shfl_xor(16,32) tree sum. log_softmax split into its own
// kernel (partitioned prop can't see full rows). mm retiled 80->48 rows
// (LDS 25KB -> 6 blocks/CU).

#define N_NODES 50000
#define N_EDGES 800000
#define NB_SCAN 196          // ceil(50000/256)

// ---------------- graph preprocessing ----------------

__global__ void count_deg_kernel(const int* __restrict__ col, int* __restrict__ deg, int e) {
    int i = blockIdx.x * 256 + threadIdx.x;
    if (i < e) atomicAdd(&deg[col[i]], 1);
}

__global__ void scan1_kernel(const int* __restrict__ deg, int* __restrict__ bsum,
                             float* __restrict__ dinv) {
    __shared__ int sd[256];
    int tid = threadIdx.x;
    int i = blockIdx.x * 256 + tid;
    int v = (i < N_NODES) ? deg[i] : 0;
    if (i < N_NODES) dinv[i] = (v > 0) ? (1.0f / sqrtf((float)v)) : 0.f;
    sd[tid] = v;
    __syncthreads();
    for (int o = 128; o > 0; o >>= 1) {
        if (tid < o) sd[tid] += sd[tid + o];
        __syncthreads();
    }
    if (tid == 0) bsum[blockIdx.x] = sd[0];
}

__global__ void scan2_kernel(int* __restrict__ bsum) {
    __shared__ int sd[256];
    int tid = threadIdx.x;
    int v = (tid < NB_SCAN) ? bsum[tid] : 0;
    sd[tid] = v;
    __syncthreads();
    for (int o = 1; o < 256; o <<= 1) {
        int t = (tid >= o) ? sd[tid - o] : 0;
        __syncthreads();
        sd[tid] += t;
        __syncthreads();
    }
    if (tid < NB_SCAN) bsum[tid] = sd[tid] - v;   // exclusive
}

__global__ void scan3_kernel(const int* __restrict__ deg, const int* __restrict__ bsum,
                             int* __restrict__ off, int* __restrict__ cursor) {
    __shared__ int sd[256];
    int tid = threadIdx.x;
    int i = blockIdx.x * 256 + tid;
    int v = (i < N_NODES) ? deg[i] : 0;
    sd[tid] = v;
    __syncthreads();
    for (int o = 1; o < 256; o <<= 1) {
        int t = (tid >= o) ? sd[tid - o] : 0;
        __syncthreads();
        sd[tid] += t;
        __syncthreads();
    }
    if (i < N_NODES) {
        int val = bsum[blockIdx.x] + sd[tid] - v;
        off[i] = val;
        cursor[i] = val;
    }
    if (i == N_NODES - 1) off[N_NODES] = N_EDGES;
}

__global__ void scatter_csr_kernel(const int* __restrict__ row, const int* __restrict__ col,
                                   const float* __restrict__ dinv, int* __restrict__ cursor,
                                   int2* __restrict__ meta, int e) {
    int i = blockIdx.x * 256 + threadIdx.x;
    if (i < e) {
        int r = row[i], c = col[i];
        int p = atomicAdd(&cursor[c], 1);
        float w = dinv[r] * dinv[c];
        meta[p] = make_int2(r, __float_as_int(w));
    }
}

// ---------------- nontemporal meta load (keep L2 for features) ----------------
__device__ inline int2 ldnt_meta(const int2* p) {
    long long v = __builtin_nontemporal_load((const long long*)p);
    int2 r;
    r.x = (int)(v & 0xffffffffLL);
    r.y = (int)(v >> 32);
    return r;
}

// -------- prop128_xcd: out[n][cg*16+c] = sum_e w[e] * h[src[e]][cg*16+c] --------
// cg = blockIdx&7 -> pinned to one XCD; per-XCD working set 50000*64B = 3.2MB (L2-fit).
// 4 waves/block, 1 node/wave; quarter-waves (q=lane>>4) cover 4 edges per iter.
__global__ void prop128_xcd(const float* __restrict__ h, const int* __restrict__ off,
                            const int2* __restrict__ meta, float* __restrict__ out) {
    const int tid = threadIdx.x;
    const int wid = tid >> 6;
    const int lane = tid & 63;
    const int q = lane >> 4, c = lane & 15;
    const int cg = blockIdx.x & 7;
    const int node = (blockIdx.x >> 3) * 4 + wid;
    int s = __builtin_amdgcn_readfirstlane(off[node]);
    int e = __builtin_amdgcn_readfirstlane(off[node + 1]);
    const float* hb = h + cg * 16 + c;

    float acc0 = 0.f, acc1 = 0.f;
    int j = s;
    for (; j + 7 < e; j += 8) {
        int2 m0 = ldnt_meta(&meta[j + q]);
        int2 m1 = ldnt_meta(&meta[j + 4 + q]);
        float v0 = hb[(size_t)m0.x * 128];
        float v1 = hb[(size_t)m1.x * 128];
        acc0 += __int_as_float(m0.y) * v0;
        acc1 += __int_as_float(m1.y) * v1;
    }
    for (; j < e; j += 4) {
        int jq = j + q;
        int2 m = ldnt_meta(&meta[jq < e ? jq : (e - 1)]);
        float w = (jq < e) ? __int_as_float(m.y) : 0.f;
        acc0 += w * hb[(size_t)m.x * 128];
    }
    float acc = acc0 + acc1;
    acc += __shfl_xor(acc, 16);
    acc += __shfl_xor(acc, 32);
    if (q == 0)
        __builtin_nontemporal_store(acc, &out[(size_t)node * 128 + cg * 16 + c]);
}

// -------- prop64_xcd: 64-wide; out = gather + yadd. cg = blockIdx&3 (XCD x -> cg x&3).
__global__ void prop64_xcd(const float* __restrict__ h, const int* __restrict__ off,
                           const int2* __restrict__ meta, const float* __restrict__ yadd,
                           float* __restrict__ out) {
    const int tid = threadIdx.x;
    const int wid = tid >> 6;
    const int lane = tid & 63;
    const int q = lane >> 4, c = lane & 15;
    const int cg = blockIdx.x & 3;
    const int node = (blockIdx.x >> 2) * 4 + wid;
    int s = __builtin_amdgcn_readfirstlane(off[node]);
    int e = __builtin_amdgcn_readfirstlane(off[node + 1]);
    const float* hb = h + cg * 16 + c;

    float acc0 = 0.f, acc1 = 0.f;
    int j = s;
    for (; j + 7 < e; j += 8) {
        int2 m0 = ldnt_meta(&meta[j + q]);
        int2 m1 = ldnt_meta(&meta[j + 4 + q]);
        float v0 = hb[(size_t)m0.x * 64];
        float v1 = hb[(size_t)m1.x * 64];
        acc0 += __int_as_float(m0.y) * v0;
        acc1 += __int_as_float(m1.y) * v1;
    }
    for (; j < e; j += 4) {
        int jq = j + q;
        int2 m = ldnt_meta(&meta[jq < e ? jq : (e - 1)]);
        float w = (jq < e) ? __int_as_float(m.y) : 0.f;
        acc0 += w * hb[(size_t)m.x * 64];
    }
    float acc = acc0 + acc1;
    acc += __shfl_xor(acc, 16);
    acc += __shfl_xor(acc, 32);
    if (q == 0) {
        size_t idx = (size_t)node * 64 + cg * 16 + c;
        __builtin_nontemporal_store(acc + yadd[idx], &out[idx]);
    }
}

// -------- logsoftmax64: out[n] = log_softmax(in[n] + bias) over 64 cols. 1 node/wave.
__global__ void logsoftmax64(const float* __restrict__ in, const float* __restrict__ bias,
                             float* __restrict__ out) {
    int tid = threadIdx.x;
    int node = blockIdx.x * 4 + (tid >> 6);
    int lane = tid & 63;
    float v = in[(size_t)node * 64 + lane] + bias[lane];
    float m = v;
    for (int d = 32; d > 0; d >>= 1) m = fmaxf(m, __shfl_xor(m, d));
    float su = expf(v - m);
    for (int d = 32; d > 0; d >>= 1) su += __shfl_xor(su, d);
    out[(size_t)node * 64 + lane] = (v - m) - logf(su);
}

// ------- mm_chain4: out = relu(sum_hop h_hop(48x128) @ W[hop][:, c0:c0+64] + bias) -------
// grid (1042, 2); LDS 25KB -> 6 blocks/CU. W from global (L2/L1-broadcast).
__global__ __launch_bounds__(256) void mm_chain4(const float* __restrict__ h0,
                                                 const float* __restrict__ h1,
                                                 const float* __restrict__ h2,
                                                 const float* __restrict__ h3,
                                                 const float* __restrict__ W,   // [4][128][128]
                                                 const float* __restrict__ bias,
                                                 float* __restrict__ outp) {
    __shared__ float hs[48 * 132];
    const int tid = threadIdx.x;
    const int tx = tid & 15;
    const int ty = tid >> 4;
    const int row0 = blockIdx.x * 48;
    const int c0 = blockIdx.y * 64;
    const int rbase = ty * 3;

    float4 acc[3];
#pragma unroll
    for (int r = 0; r < 3; ++r) acc[r] = make_float4(0.f, 0.f, 0.f, 0.f);

#pragma unroll
    for (int hop = 0; hop < 4; ++hop) {
        const float* hp = (hop == 0) ? h0 : (hop == 1) ? h1 : (hop == 2) ? h2 : h3;
        if (hop) __syncthreads();   // protect LDS before restage
        const float4* srcv = (const float4*)(hp + (size_t)row0 * 128);
        for (int i = tid; i < 1536; i += 256) {
            int r = i >> 5, cc = i & 31;
            float4 v = make_float4(0.f, 0.f, 0.f, 0.f);
            if (row0 + r < N_NODES) v = srcv[i];
            *(float4*)&hs[r * 132 + cc * 4] = v;
        }
        __syncthreads();

        const float* wp = W + (size_t)hop * 128 * 128 + c0;
#pragma unroll 2
        for (int k4 = 0; k4 < 32; ++k4) {
            float4 wv[4];
#pragma unroll
            for (int kk = 0; kk < 4; ++kk)
                wv[kk] = *(const float4*)&wp[(size_t)(k4 * 4 + kk) * 128 + tx * 4];
#pragma unroll
            for (int r = 0; r < 3; ++r) {
                float4 hv = *(const float4*)&hs[(rbase + r) * 132 + k4 * 4];
                acc[r].x += hv.x * wv[0].x + hv.y * wv[1].x + hv.z * wv[2].x + hv.w * wv[3].x;
                acc[r].y += hv.x * wv[0].y + hv.y * wv[1].y + hv.z * wv[2].y + hv.w * wv[3].y;
                acc[r].z += hv.x * wv[0].z + hv.y * wv[1].z + hv.z * wv[2].z + hv.w * wv[3].z;
                acc[r].w += hv.x * wv[0].w + hv.y * wv[1].w + hv.z * wv[2].w + hv.w * wv[3].w;
            }
        }
    }

    float4 bv = *(const float4*)&bias[c0 + tx * 4];
#pragma unroll
    for (int r = 0; r < 3; ++r) {
        int rowg = row0 + rbase + r;
        if (rowg < N_NODES) {
            float4 v = acc[r];
            v.x = fmaxf(v.x + bv.x, 0.f);
            v.y = fmaxf(v.y + bv.y, 0.f);
            v.z = fmaxf(v.z + bv.z, 0.f);
            v.w = fmaxf(v.w + bv.w, 0.f);
            *(float4*)&outp[(size_t)rowg * 128 + c0 + tx * 4] = v;
        }
    }
}

// ---------------- mm_y64: y[hop] = h @ W[hop]; grid (1042, 4) ----------------
__global__ __launch_bounds__(256) void mm_y64(const float* __restrict__ h,
                                              const float* __restrict__ W,   // [4][128][64]
                                              float* __restrict__ y) {       // [4][N][64]
    __shared__ float hs[48 * 132];
    const int tid = threadIdx.x;
    const int tx = tid & 15;
    const int ty = tid >> 4;
    const int row0 = blockIdx.x * 48;
    const int hop = blockIdx.y;
    const int rbase = ty * 3;

    const float4* srcv = (const float4*)(h + (size_t)row0 * 128);
    for (int i = tid; i < 1536; i += 256) {
        int r = i >> 5, cc = i & 31;
        float4 v = make_float4(0.f, 0.f, 0.f, 0.f);
        if (row0 + r < N_NODES) v = srcv[i];
        *(float4*)&hs[r * 132 + cc * 4] = v;
    }
    __syncthreads();

    const float4* Wv = (const float4*)(W + (size_t)hop * 128 * 64);

    float4 acc[3];
#pragma unroll
    for (int r = 0; r < 3; ++r) acc[r] = make_float4(0.f, 0.f, 0.f, 0.f);

#pragma unroll 2
    for (int k4 = 0; k4 < 32; ++k4) {
        float4 wv[4];
#pragma unroll
        for (int kk = 0; kk < 4; ++kk)
            wv[kk] = Wv[(size_t)(k4 * 4 + kk) * 16 + tx];
#pragma unroll
        for (int r = 0; r < 3; ++r) {
            float4 hv = *(const float4*)&hs[(rbase + r) * 132 + k4 * 4];
            acc[r].x += hv.x * wv[0].x + hv.y * wv[1].x + hv.z * wv[2].x + hv.w * wv[3].x;
            acc[r].y += hv.x * wv[0].y + hv.y * wv[1].y + hv.z * wv[2].y + hv.w * wv[3].y;
            acc[r].z += hv.x * wv[0].z + hv.y * wv[1].z + hv.z * wv[2].z + hv.w * wv[3].z;
            acc[r].w += hv.x * wv[0].w + hv.y * wv[1].w + hv.z * wv[2].w + hv.w * wv[3].w;
        }
    }

    float* yp = y + (size_t)hop * N_NODES * 64;
#pragma unroll
    for (int r = 0; r < 3; ++r) {
        int rowg = row0 + rbase + r;
        if (rowg < N_NODES)
            *(float4*)&yp[(size_t)rowg * 64 + tx * 4] = acc[r];
    }
}

// ---------------- launch ----------------

extern "C" void kernel_launch(void* const* d_in, const int* in_sizes, int n_in,
                              void* d_out, int out_size, void* d_ws, size_t ws_size,
                              hipStream_t stream) {
    const float* x  = (const float*)d_in[0];
    const int*   ei = (const int*)d_in[1];
    const float* W1 = (const float*)d_in[2];
    const float* b1 = (const float*)d_in[3];
    const float* W2 = (const float*)d_in[4];
    const float* b2 = (const float*)d_in[5];
    float* out = (float*)d_out;

    const int* row = ei;             // edge_index[0]
    const int* col = ei + N_EDGES;   // edge_index[1]

    char* ws_base = (char*)d_ws;
    size_t o = 0;
    auto carve = [&](size_t bytes) {
        void* p = ws_base + o;
        o = (o + bytes + 511) & ~(size_t)511;
        return p;
    };
    int*   deg    = (int*)carve(N_NODES * 4);
    float* dinv   = (float*)carve(N_NODES * 4);
    int*   off    = (int*)carve((N_NODES + 1) * 4);
    int*   cursor = (int*)carve(N_NODES * 4);
    int*   bsum   = (int*)carve(NB_SCAN * 4);
    int2*  meta   = (int2*)carve((size_t)N_EDGES * 8);
    float* A      = (float*)carve((size_t)N_NODES * 128 * 4);
    float* B      = (float*)carve((size_t)N_NODES * 128 * 4);
    float* C      = (float*)carve((size_t)N_NODES * 128 * 4);
    float* hid    = (float*)carve((size_t)N_NODES * 128 * 4);
    float* y2     = (float*)carve((size_t)4 * N_NODES * 64 * 4);   // [4][N][64]
    float* T2     = (float*)carve((size_t)N_NODES * 64 * 4);
    float* TMP    = (float*)carve((size_t)N_NODES * 64 * 4);

    float* y2_0 = y2;
    float* y2_1 = y2 + (size_t)1 * N_NODES * 64;
    float* y2_2 = y2 + (size_t)2 * N_NODES * 64;
    float* y2_3 = y2 + (size_t)3 * N_NODES * 64;
    float* S2   = y2_3;   // reuse once y2_3 is consumed

    const int nb_e = (N_EDGES + 255) / 256;   // 3125

    // graph preprocessing
    hipMemsetAsync(deg, 0, N_NODES * 4, stream);
    count_deg_kernel<<<nb_e, 256, 0, stream>>>(col, deg, N_EDGES);
    scan1_kernel<<<NB_SCAN, 256, 0, stream>>>(deg, bsum, dinv);
    scan2_kernel<<<1, 256, 0, stream>>>(bsum);
    scan3_kernel<<<NB_SCAN, 256, 0, stream>>>(deg, bsum, off, cursor);
    scatter_csr_kernel<<<nb_e, 256, 0, stream>>>(row, col, dinv, cursor, meta, N_EDGES);

    // ----- layer 1: chain props (XCD-partitioned), then one fused K=512 matmul -> hid
    prop128_xcd<<<100000, 256, 0, stream>>>(x, off, meta, A);
    prop128_xcd<<<100000, 256, 0, stream>>>(A, off, meta, B);
    prop128_xcd<<<100000, 256, 0, stream>>>(B, off, meta, C);
    mm_chain4<<<dim3(1042, 2), 256, 0, stream>>>(x, A, B, C, W1, b1, hid);

    // ----- layer 2 (Horner): out = log_softmax(z0 + A(z1 + A(z2 + A z3)) + b2)
    mm_y64<<<dim3(1042, 4), 256, 0, stream>>>(hid, W2, y2);
    prop64_xcd<<<50000, 256, 0, stream>>>(y2_3, off, meta, y2_2, T2);
    prop64_xcd<<<50000, 256, 0, stream>>>(T2,   off, meta, y2_1, S2);
    prop64_xcd<<<50000, 256, 0, stream>>>(S2,   off, meta, y2_0, TMP);
    logsoftmax64<<<12500, 256, 0, stream>>>(TMP, b2, out);
}

// Round 8
// 635.045 us; speedup vs baseline: 2.1254x; 2.1254x over previous
//
#include <hip/hip_runtime.h>
#include <math.h>

// TAGCN 2-layer GNN on MI355X.
// R8 = R6 structure (the 583us config) + two regime-matched fixes:
// - props: unroll 16 (16 independent gathers in flight; latency-bound regime,
//   VALUBusy was 21%) with scalarized CSR bounds.
// - mm kernels: explicit next-k4 register prefetch of W (W-load latency was
//   capping VALUBusy at 53%).
// R7's XCD column partitioning is abandoned: 50000x128B = 6.4MB/XCD > 4MiB L2,
// and 64B slices split cache lines -- measured 3.4x regression.

#define N_NODES 50000
#define N_EDGES 800000
#define NB_SCAN 196          // ceil(50000/256)

// ---------------- graph preprocessing ----------------

__global__ void count_deg_kernel(const int* __restrict__ col, int* __restrict__ deg, int e) {
    int i = blockIdx.x * 256 + threadIdx.x;
    if (i < e) atomicAdd(&deg[col[i]], 1);
}

__global__ void scan1_kernel(const int* __restrict__ deg, int* __restrict__ bsum,
                             float* __restrict__ dinv) {
    __shared__ int sd[256];
    int tid = threadIdx.x;
    int i = blockIdx.x * 256 + tid;
    int v = (i < N_NODES) ? deg[i] : 0;
    if (i < N_NODES) dinv[i] = (v > 0) ? (1.0f / sqrtf((float)v)) : 0.f;
    sd[tid] = v;
    __syncthreads();
    for (int o = 128; o > 0; o >>= 1) {
        if (tid < o) sd[tid] += sd[tid + o];
        __syncthreads();
    }
    if (tid == 0) bsum[blockIdx.x] = sd[0];
}

__global__ void scan2_kernel(int* __restrict__ bsum) {
    __shared__ int sd[256];
    int tid = threadIdx.x;
    int v = (tid < NB_SCAN) ? bsum[tid] : 0;
    sd[tid] = v;
    __syncthreads();
    for (int o = 1; o < 256; o <<= 1) {
        int t = (tid >= o) ? sd[tid - o] : 0;
        __syncthreads();
        sd[tid] += t;
        __syncthreads();
    }
    if (tid < NB_SCAN) bsum[tid] = sd[tid] - v;   // exclusive
}

__global__ void scan3_kernel(const int* __restrict__ deg, const int* __restrict__ bsum,
                             int* __restrict__ off, int* __restrict__ cursor) {
    __shared__ int sd[256];
    int tid = threadIdx.x;
    int i = blockIdx.x * 256 + tid;
    int v = (i < N_NODES) ? deg[i] : 0;
    sd[tid] = v;
    __syncthreads();
    for (int o = 1; o < 256; o <<= 1) {
        int t = (tid >= o) ? sd[tid - o] : 0;
        __syncthreads();
        sd[tid] += t;
        __syncthreads();
    }
    if (i < N_NODES) {
        int val = bsum[blockIdx.x] + sd[tid] - v;
        off[i] = val;
        cursor[i] = val;
    }
    if (i == N_NODES - 1) off[N_NODES] = N_EDGES;
}

__global__ void scatter_csr_kernel(const int* __restrict__ row, const int* __restrict__ col,
                                   const float* __restrict__ dinv, int* __restrict__ cursor,
                                   int2* __restrict__ meta, int e) {
    int i = blockIdx.x * 256 + threadIdx.x;
    if (i < e) {
        int r = row[i], c = col[i];
        int p = atomicAdd(&cursor[c], 1);
        float w = dinv[r] * dinv[c];
        meta[p] = make_int2(r, __float_as_int(w));
    }
}

// -------- prop128: out = A*h (+ yadd) (+bias,relu). 1 node / 64-lane wave, float2/lane.
// 16 independent gathers in flight (latency-bound regime); scalarized CSR bounds.
template <int EPI, bool HASY>   // EPI: 0 = none, 1 = +bias, relu
__global__ void prop128(const float* __restrict__ h, const int* __restrict__ off,
                        const int2* __restrict__ meta, const float* __restrict__ yadd,
                        const float* __restrict__ bias, float* __restrict__ out) {
    int node = blockIdx.x * 4 + (threadIdx.x >> 6);
    int lane = threadIdx.x & 63;
    int s = __builtin_amdgcn_readfirstlane(off[node]);
    int e = __builtin_amdgcn_readfirstlane(off[node + 1]);
    const float2* h2 = (const float2*)h;

    float2 yv = make_float2(0.f, 0.f);
    if (HASY) yv = ((const float2*)yadd)[node * 64 + lane];

    float2 acc[4];
#pragma unroll
    for (int u = 0; u < 4; ++u) acc[u] = make_float2(0.f, 0.f);

    int j = s;
    for (; j + 15 < e; j += 16) {
        int2 m[16];
        float2 v[16];
#pragma unroll
        for (int u = 0; u < 16; ++u) m[u] = meta[j + u];
#pragma unroll
        for (int u = 0; u < 16; ++u) v[u] = h2[(size_t)m[u].x * 64 + lane];
#pragma unroll
        for (int u = 0; u < 16; ++u) {
            float w = __int_as_float(m[u].y);
            acc[u & 3].x += w * v[u].x;
            acc[u & 3].y += w * v[u].y;
        }
    }
    for (; j + 3 < e; j += 4) {
        int2 m[4];
        float2 v[4];
#pragma unroll
        for (int u = 0; u < 4; ++u) m[u] = meta[j + u];
#pragma unroll
        for (int u = 0; u < 4; ++u) v[u] = h2[(size_t)m[u].x * 64 + lane];
#pragma unroll
        for (int u = 0; u < 4; ++u) {
            float w = __int_as_float(m[u].y);
            acc[u].x += w * v[u].x;
            acc[u].y += w * v[u].y;
        }
    }
    for (; j < e; ++j) {
        int2 m = meta[j];
        float2 v = h2[(size_t)m.x * 64 + lane];
        float w = __int_as_float(m.y);
        acc[0].x += w * v.x;
        acc[0].y += w * v.y;
    }
    float2 r = make_float2((acc[0].x + acc[1].x) + (acc[2].x + acc[3].x) + yv.x,
                           (acc[0].y + acc[1].y) + (acc[2].y + acc[3].y) + yv.y);
    if (EPI == 1) {
        float2 bv = ((const float2*)bias)[lane];
        r.x = fmaxf(r.x + bv.x, 0.f);
        r.y = fmaxf(r.y + bv.y, 0.f);
    }
    ((float2*)out)[node * 64 + lane] = r;
}

// -------- prop64: 64-wide arrays. 1 node / 64-lane wave, float/lane. Unroll 16.
template <int EPI>   // 0 = plain accumulate, 2 = +bias, log_softmax
__global__ void prop64(const float* __restrict__ h, const int* __restrict__ off,
                       const int2* __restrict__ meta, const float* __restrict__ yadd,
                       const float* __restrict__ bias, float* __restrict__ out) {
    int node = blockIdx.x * 4 + (threadIdx.x >> 6);
    int lane = threadIdx.x & 63;
    int s = __builtin_amdgcn_readfirstlane(off[node]);
    int e = __builtin_amdgcn_readfirstlane(off[node + 1]);

    float yv = yadd[(size_t)node * 64 + lane];   // hoisted

    float acc[4] = {0.f, 0.f, 0.f, 0.f};
    int j = s;
    for (; j + 15 < e; j += 16) {
        int2 m[16];
        float v[16];
#pragma unroll
        for (int u = 0; u < 16; ++u) m[u] = meta[j + u];
#pragma unroll
        for (int u = 0; u < 16; ++u) v[u] = h[(size_t)m[u].x * 64 + lane];
#pragma unroll
        for (int u = 0; u < 16; ++u) acc[u & 3] += __int_as_float(m[u].y) * v[u];
    }
    for (; j + 3 < e; j += 4) {
        int2 m[4];
        float v[4];
#pragma unroll
        for (int u = 0; u < 4; ++u) m[u] = meta[j + u];
#pragma unroll
        for (int u = 0; u < 4; ++u) v[u] = h[(size_t)m[u].x * 64 + lane];
#pragma unroll
        for (int u = 0; u < 4; ++u) acc[u] += __int_as_float(m[u].y) * v[u];
    }
    for (; j < e; ++j) {
        int2 m = meta[j];
        acc[0] += __int_as_float(m.y) * h[(size_t)m.x * 64 + lane];
    }
    float v = (acc[0] + acc[1]) + (acc[2] + acc[3]) + yv;
    if (EPI == 2) {
        v += bias[lane];
        float m = v;
        for (int d = 32; d > 0; d >>= 1) m = fmaxf(m, __shfl_xor(m, d));
        float su = expf(v - m);
        for (int d = 32; d > 0; d >>= 1) su += __shfl_xor(su, d);
        v = (v - m) - logf(su);
    }
    out[(size_t)node * 64 + lane] = v;
}

// ------- mm_chain4: out = relu(sum_hop h_hop(48x128) @ W[hop][:, c0:c0+64] + bias) -------
// grid (1042, 2); LDS 25KB -> 6 blocks/CU. W from L2 with next-k4 register prefetch.
__global__ __launch_bounds__(256) void mm_chain4(const float* __restrict__ h0,
                                                 const float* __restrict__ h1,
                                                 const float* __restrict__ h2,
                                                 const float* __restrict__ h3,
                                                 const float* __restrict__ W,   // [4][128][128]
                                                 const float* __restrict__ bias,
                                                 float* __restrict__ outp) {
    __shared__ float hs[48 * 132];
    const int tid = threadIdx.x;
    const int tx = tid & 15;
    const int ty = tid >> 4;
    const int row0 = blockIdx.x * 48;
    const int c0 = blockIdx.y * 64;
    const int rbase = ty * 3;

    float4 acc[3];
#pragma unroll
    for (int r = 0; r < 3; ++r) acc[r] = make_float4(0.f, 0.f, 0.f, 0.f);

#pragma unroll
    for (int hop = 0; hop < 4; ++hop) {
        const float* hp = (hop == 0) ? h0 : (hop == 1) ? h1 : (hop == 2) ? h2 : h3;
        if (hop) __syncthreads();   // protect LDS before restage
        const float4* srcv = (const float4*)(hp + (size_t)row0 * 128);
        for (int i = tid; i < 1536; i += 256) {
            int r = i >> 5, cc = i & 31;
            float4 v = make_float4(0.f, 0.f, 0.f, 0.f);
            if (row0 + r < N_NODES) v = srcv[i];
            *(float4*)&hs[r * 132 + cc * 4] = v;
        }
        __syncthreads();

        const float* wp = W + (size_t)hop * 128 * 128 + c0;
        float4 wv[4], wn[4];
#pragma unroll
        for (int kk = 0; kk < 4; ++kk)
            wv[kk] = *(const float4*)&wp[(size_t)kk * 128 + tx * 4];
#pragma unroll 2
        for (int k4 = 0; k4 < 32; ++k4) {
            if (k4 < 31) {
#pragma unroll
                for (int kk = 0; kk < 4; ++kk)
                    wn[kk] = *(const float4*)&wp[(size_t)((k4 + 1) * 4 + kk) * 128 + tx * 4];
            }
#pragma unroll
            for (int r = 0; r < 3; ++r) {
                float4 hv = *(const float4*)&hs[(rbase + r) * 132 + k4 * 4];
                acc[r].x += hv.x * wv[0].x + hv.y * wv[1].x + hv.z * wv[2].x + hv.w * wv[3].x;
                acc[r].y += hv.x * wv[0].y + hv.y * wv[1].y + hv.z * wv[2].y + hv.w * wv[3].y;
                acc[r].z += hv.x * wv[0].z + hv.y * wv[1].z + hv.z * wv[2].z + hv.w * wv[3].z;
                acc[r].w += hv.x * wv[0].w + hv.y * wv[1].w + hv.z * wv[2].w + hv.w * wv[3].w;
            }
#pragma unroll
            for (int kk = 0; kk < 4; ++kk) wv[kk] = wn[kk];
        }
    }

    float4 bv = *(const float4*)&bias[c0 + tx * 4];
#pragma unroll
    for (int r = 0; r < 3; ++r) {
        int rowg = row0 + rbase + r;
        if (rowg < N_NODES) {
            float4 v = acc[r];
            v.x = fmaxf(v.x + bv.x, 0.f);
            v.y = fmaxf(v.y + bv.y, 0.f);
            v.z = fmaxf(v.z + bv.z, 0.f);
            v.w = fmaxf(v.w + bv.w, 0.f);
            *(float4*)&outp[(size_t)rowg * 128 + c0 + tx * 4] = v;
        }
    }
}

// ---------------- mm_y64: y[hop] = h @ W[hop]; grid (1042, 4), W prefetch ----------------
__global__ __launch_bounds__(256) void mm_y64(const float* __restrict__ h,
                                              const float* __restrict__ W,   // [4][128][64]
                                              float* __restrict__ y) {       // [4][N][64]
    __shared__ float hs[48 * 132];
    const int tid = threadIdx.x;
    const int tx = tid & 15;
    const int ty = tid >> 4;
    const int row0 = blockIdx.x * 48;
    const int hop = blockIdx.y;
    const int rbase = ty * 3;

    const float4* srcv = (const float4*)(h + (size_t)row0 * 128);
    for (int i = tid; i < 1536; i += 256) {
        int r = i >> 5, cc = i & 31;
        float4 v = make_float4(0.f, 0.f, 0.f, 0.f);
        if (row0 + r < N_NODES) v = srcv[i];
        *(float4*)&hs[r * 132 + cc * 4] = v;
    }
    __syncthreads();

    const float4* Wv = (const float4*)(W + (size_t)hop * 128 * 64);

    float4 acc[3];
#pragma unroll
    for (int r = 0; r < 3; ++r) acc[r] = make_float4(0.f, 0.f, 0.f, 0.f);

    float4 wv[4], wn[4];
#pragma unroll
    for (int kk = 0; kk < 4; ++kk) wv[kk] = Wv[(size_t)kk * 16 + tx];
#pragma unroll 2
    for (int k4 = 0; k4 < 32; ++k4) {
        if (k4 < 31) {
#pragma unroll
            for (int kk = 0; kk < 4; ++kk)
                wn[kk] = Wv[(size_t)((k4 + 1) * 4 + kk) * 16 + tx];
        }
#pragma unroll
        for (int r = 0; r < 3; ++r) {
            float4 hv = *(const float4*)&hs[(rbase + r) * 132 + k4 * 4];
            acc[r].x += hv.x * wv[0].x + hv.y * wv[1].x + hv.z * wv[2].x + hv.w * wv[3].x;
            acc[r].y += hv.x * wv[0].y + hv.y * wv[1].y + hv.z * wv[2].y + hv.w * wv[3].y;
            acc[r].z += hv.x * wv[0].z + hv.y * wv[1].z + hv.z * wv[2].z + hv.w * wv[3].z;
            acc[r].w += hv.x * wv[0].w + hv.y * wv[1].w + hv.z * wv[2].w + hv.w * wv[3].w;
        }
#pragma unroll
        for (int kk = 0; kk < 4; ++kk) wv[kk] = wn[kk];
    }

    float* yp = y + (size_t)hop * N_NODES * 64;
#pragma unroll
    for (int r = 0; r < 3; ++r) {
        int rowg = row0 + rbase + r;
        if (rowg < N_NODES)
            *(float4*)&yp[(size_t)rowg * 64 + tx * 4] = acc[r];
    }
}

// ---------------- launch ----------------

extern "C" void kernel_launch(void* const* d_in, const int* in_sizes, int n_in,
                              void* d_out, int out_size, void* d_ws, size_t ws_size,
                              hipStream_t stream) {
    const float* x  = (const float*)d_in[0];
    const int*   ei = (const int*)d_in[1];
    const float* W1 = (const float*)d_in[2];
    const float* b1 = (const float*)d_in[3];
    const float* W2 = (const float*)d_in[4];
    const float* b2 = (const float*)d_in[5];
    float* out = (float*)d_out;

    const int* row = ei;             // edge_index[0]
    const int* col = ei + N_EDGES;   // edge_index[1]

    char* ws_base = (char*)d_ws;
    size_t o = 0;
    auto carve = [&](size_t bytes) {
        void* p = ws_base + o;
        o = (o + bytes + 511) & ~(size_t)511;
        return p;
    };
    int*   deg    = (int*)carve(N_NODES * 4);
    float* dinv   = (float*)carve(N_NODES * 4);
    int*   off    = (int*)carve((N_NODES + 1) * 4);
    int*   cursor = (int*)carve(N_NODES * 4);
    int*   bsum   = (int*)carve(NB_SCAN * 4);
    int2*  meta   = (int2*)carve((size_t)N_EDGES * 8);
    float* A      = (float*)carve((size_t)N_NODES * 128 * 4);
    float* B      = (float*)carve((size_t)N_NODES * 128 * 4);
    float* C      = (float*)carve((size_t)N_NODES * 128 * 4);
    float* hid    = (float*)carve((size_t)N_NODES * 128 * 4);
    float* y2     = (float*)carve((size_t)4 * N_NODES * 64 * 4);   // [4][N][64]
    float* T2     = (float*)carve((size_t)N_NODES * 64 * 4);

    float* y2_0 = y2;
    float* y2_1 = y2 + (size_t)1 * N_NODES * 64;
    float* y2_2 = y2 + (size_t)2 * N_NODES * 64;
    float* y2_3 = y2 + (size_t)3 * N_NODES * 64;
    float* S2   = y2_3;   // reuse once y2_3 is consumed

    const int nb_e = (N_EDGES + 255) / 256;   // 3125

    // graph preprocessing
    hipMemsetAsync(deg, 0, N_NODES * 4, stream);
    count_deg_kernel<<<nb_e, 256, 0, stream>>>(col, deg, N_EDGES);
    scan1_kernel<<<NB_SCAN, 256, 0, stream>>>(deg, bsum, dinv);
    scan2_kernel<<<1, 256, 0, stream>>>(bsum);
    scan3_kernel<<<NB_SCAN, 256, 0, stream>>>(deg, bsum, off, cursor);
    scatter_csr_kernel<<<nb_e, 256, 0, stream>>>(row, col, dinv, cursor, meta, N_EDGES);

    // ----- layer 1: chain props, then one fused K=512 matmul -> hid
    prop128<0, false><<<12500, 256, 0, stream>>>(x, off, meta, nullptr, nullptr, A);
    prop128<0, false><<<12500, 256, 0, stream>>>(A, off, meta, nullptr, nullptr, B);
    prop128<0, false><<<12500, 256, 0, stream>>>(B, off, meta, nullptr, nullptr, C);
    mm_chain4<<<dim3(1042, 2), 256, 0, stream>>>(x, A, B, C, W1, b1, hid);

    // ----- layer 2 (Horner): out = log_softmax(z0 + A(z1 + A(z2 + A z3)) + b2)
    mm_y64<<<dim3(1042, 4), 256, 0, stream>>>(hid, W2, y2);
    prop64<0><<<12500, 256, 0, stream>>>(y2_3, off, meta, y2_2, nullptr, T2);
    prop64<0><<<12500, 256, 0, stream>>>(T2,   off, meta, y2_1, nullptr, S2);
    prop64<2><<<12500, 256, 0, stream>>>(S2,   off, meta, y2_0, b2,      out);
}

// Round 9
// 478.585 us; speedup vs baseline: 2.8203x; 1.3269x over previous
//
#include <hip/hip_runtime.h>
#include <math.h>

// TAGCN 2-layer GNN on MI355X.
// R9 = R6/R8 structure with both matmuls moved to bf16 MFMA (16x16x32, fp32 acc):
// - W pre-transposed+converted once to col-major bf16 W^T[hop][col][k] -> B-frags
//   are contiguous 16B loads.
// - h tiles converted fp32->bf16 during LDS staging, 16B-chunk XOR swizzle
//   (T2) on both write and read sides.
// - 32-row tiles, grid 1563 (>=6 blocks/CU; R5/R8 starvation lesson).
// Props kept from R8 (miss-throughput-bound; ILP changes measured neutral).

#define N_NODES 50000
#define N_EDGES 800000
#define NB_SCAN 196          // ceil(50000/256)

typedef __attribute__((ext_vector_type(8))) short bf16x8;
typedef __attribute__((ext_vector_type(4))) float f32x4;

__device__ inline ushort f2b(float x) {   // fp32 -> bf16 bits, RTNE
    unsigned u = __float_as_uint(x);
    return (ushort)((u + 0x7FFFu + ((u >> 16) & 1u)) >> 16);
}

// ---------------- graph preprocessing ----------------

__global__ void count_deg_kernel(const int* __restrict__ col, int* __restrict__ deg, int e) {
    int i = blockIdx.x * 256 + threadIdx.x;
    if (i < e) atomicAdd(&deg[col[i]], 1);
}

__global__ void scan1_kernel(const int* __restrict__ deg, int* __restrict__ bsum,
                             float* __restrict__ dinv) {
    __shared__ int sd[256];
    int tid = threadIdx.x;
    int i = blockIdx.x * 256 + tid;
    int v = (i < N_NODES) ? deg[i] : 0;
    if (i < N_NODES) dinv[i] = (v > 0) ? (1.0f / sqrtf((float)v)) : 0.f;
    sd[tid] = v;
    __syncthreads();
    for (int o = 128; o > 0; o >>= 1) {
        if (tid < o) sd[tid] += sd[tid + o];
        __syncthreads();
    }
    if (tid == 0) bsum[blockIdx.x] = sd[0];
}

__global__ void scan2_kernel(int* __restrict__ bsum) {
    __shared__ int sd[256];
    int tid = threadIdx.x;
    int v = (tid < NB_SCAN) ? bsum[tid] : 0;
    sd[tid] = v;
    __syncthreads();
    for (int o = 1; o < 256; o <<= 1) {
        int t = (tid >= o) ? sd[tid - o] : 0;
        __syncthreads();
        sd[tid] += t;
        __syncthreads();
    }
    if (tid < NB_SCAN) bsum[tid] = sd[tid] - v;   // exclusive
}

__global__ void scan3_kernel(const int* __restrict__ deg, const int* __restrict__ bsum,
                             int* __restrict__ off, int* __restrict__ cursor) {
    __shared__ int sd[256];
    int tid = threadIdx.x;
    int i = blockIdx.x * 256 + tid;
    int v = (i < N_NODES) ? deg[i] : 0;
    sd[tid] = v;
    __syncthreads();
    for (int o = 1; o < 256; o <<= 1) {
        int t = (tid >= o) ? sd[tid - o] : 0;
        __syncthreads();
        sd[tid] += t;
        __syncthreads();
    }
    if (i < N_NODES) {
        int val = bsum[blockIdx.x] + sd[tid] - v;
        off[i] = val;
        cursor[i] = val;
    }
    if (i == N_NODES - 1) off[N_NODES] = N_EDGES;
}

__global__ void scatter_csr_kernel(const int* __restrict__ row, const int* __restrict__ col,
                                   const float* __restrict__ dinv, int* __restrict__ cursor,
                                   int2* __restrict__ meta, int e) {
    int i = blockIdx.x * 256 + threadIdx.x;
    if (i < e) {
        int r = row[i], c = col[i];
        int p = atomicAdd(&cursor[c], 1);
        float w = dinv[r] * dinv[c];
        meta[p] = make_int2(r, __float_as_int(w));
    }
}

// -------- W transpose + bf16 convert: W[4][128][NC] -> WT[4][NC][128] --------
template <int NC>
__global__ void wtrans(const float* __restrict__ W, ushort* __restrict__ WT) {
    int idx = blockIdx.x * 256 + threadIdx.x;   // idx = ((hop*NC + c)*128 + k)
    if (idx < 4 * 128 * NC) {
        int k = idx & 127;
        int hc = idx >> 7;
        int c = hc % NC;
        int hop = hc / NC;
        WT[idx] = f2b(W[((size_t)hop * 128 + k) * NC + c]);
    }
}

// -------- prop128: out = A*h. 1 node / 64-lane wave, float2/lane, 16 gathers in flight.
template <int EPI, bool HASY>
__global__ void prop128(const float* __restrict__ h, const int* __restrict__ off,
                        const int2* __restrict__ meta, const float* __restrict__ yadd,
                        const float* __restrict__ bias, float* __restrict__ out) {
    int node = blockIdx.x * 4 + (threadIdx.x >> 6);
    int lane = threadIdx.x & 63;
    int s = __builtin_amdgcn_readfirstlane(off[node]);
    int e = __builtin_amdgcn_readfirstlane(off[node + 1]);
    const float2* h2 = (const float2*)h;

    float2 yv = make_float2(0.f, 0.f);
    if (HASY) yv = ((const float2*)yadd)[node * 64 + lane];

    float2 acc[4];
#pragma unroll
    for (int u = 0; u < 4; ++u) acc[u] = make_float2(0.f, 0.f);

    int j = s;
    for (; j + 15 < e; j += 16) {
        int2 m[16];
        float2 v[16];
#pragma unroll
        for (int u = 0; u < 16; ++u) m[u] = meta[j + u];
#pragma unroll
        for (int u = 0; u < 16; ++u) v[u] = h2[(size_t)m[u].x * 64 + lane];
#pragma unroll
        for (int u = 0; u < 16; ++u) {
            float w = __int_as_float(m[u].y);
            acc[u & 3].x += w * v[u].x;
            acc[u & 3].y += w * v[u].y;
        }
    }
    for (; j + 3 < e; j += 4) {
        int2 m[4];
        float2 v[4];
#pragma unroll
        for (int u = 0; u < 4; ++u) m[u] = meta[j + u];
#pragma unroll
        for (int u = 0; u < 4; ++u) v[u] = h2[(size_t)m[u].x * 64 + lane];
#pragma unroll
        for (int u = 0; u < 4; ++u) {
            float w = __int_as_float(m[u].y);
            acc[u].x += w * v[u].x;
            acc[u].y += w * v[u].y;
        }
    }
    for (; j < e; ++j) {
        int2 m = meta[j];
        float2 v = h2[(size_t)m.x * 64 + lane];
        float w = __int_as_float(m.y);
        acc[0].x += w * v.x;
        acc[0].y += w * v.y;
    }
    float2 r = make_float2((acc[0].x + acc[1].x) + (acc[2].x + acc[3].x) + yv.x,
                           (acc[0].y + acc[1].y) + (acc[2].y + acc[3].y) + yv.y);
    if (EPI == 1) {
        float2 bv = ((const float2*)bias)[lane];
        r.x = fmaxf(r.x + bv.x, 0.f);
        r.y = fmaxf(r.y + bv.y, 0.f);
    }
    ((float2*)out)[node * 64 + lane] = r;
}

// -------- prop64: 64-wide arrays. 1 node / 64-lane wave, float/lane.
template <int EPI>
__global__ void prop64(const float* __restrict__ h, const int* __restrict__ off,
                       const int2* __restrict__ meta, const float* __restrict__ yadd,
                       const float* __restrict__ bias, float* __restrict__ out) {
    int node = blockIdx.x * 4 + (threadIdx.x >> 6);
    int lane = threadIdx.x & 63;
    int s = __builtin_amdgcn_readfirstlane(off[node]);
    int e = __builtin_amdgcn_readfirstlane(off[node + 1]);

    float yv = yadd[(size_t)node * 64 + lane];

    float acc[4] = {0.f, 0.f, 0.f, 0.f};
    int j = s;
    for (; j + 15 < e; j += 16) {
        int2 m[16];
        float v[16];
#pragma unroll
        for (int u = 0; u < 16; ++u) m[u] = meta[j + u];
#pragma unroll
        for (int u = 0; u < 16; ++u) v[u] = h[(size_t)m[u].x * 64 + lane];
#pragma unroll
        for (int u = 0; u < 16; ++u) acc[u & 3] += __int_as_float(m[u].y) * v[u];
    }
    for (; j + 3 < e; j += 4) {
        int2 m[4];
        float v[4];
#pragma unroll
        for (int u = 0; u < 4; ++u) m[u] = meta[j + u];
#pragma unroll
        for (int u = 0; u < 4; ++u) v[u] = h[(size_t)m[u].x * 64 + lane];
#pragma unroll
        for (int u = 0; u < 4; ++u) acc[u] += __int_as_float(m[u].y) * v[u];
    }
    for (; j < e; ++j) {
        int2 m = meta[j];
        acc[0] += __int_as_float(m.y) * h[(size_t)m.x * 64 + lane];
    }
    float v = (acc[0] + acc[1]) + (acc[2] + acc[3]) + yv;
    if (EPI == 2) {
        v += bias[lane];
        float m = v;
        for (int d = 32; d > 0; d >>= 1) m = fmaxf(m, __shfl_xor(m, d));
        float su = expf(v - m);
        for (int d = 32; d > 0; d >>= 1) su += __shfl_xor(su, d);
        v = (v - m) - logf(su);
    }
    out[(size_t)node * 64 + lane] = v;
}

// ---- stage one 32x128 fp32 tile -> bf16 LDS with 16B-chunk XOR swizzle ----
__device__ inline void stage_tile_bf16(ushort* hs, const float* hp, int row0, int tid) {
    const float4* srcv = (const float4*)(hp + (size_t)row0 * 128);
    for (int i = tid; i < 1024; i += 256) {   // 32 rows x 32 float4
        int r = i >> 5, cq = i & 31;
        float4 v = make_float4(0.f, 0.f, 0.f, 0.f);
        if (row0 + r < N_NODES) v = srcv[i];
        ushort4 b;
        b.x = f2b(v.x); b.y = f2b(v.y); b.z = f2b(v.z); b.w = f2b(v.w);
        int pc = (cq >> 1) ^ (r & 7);         // swizzle 16B chunk index
        *(ushort4*)&hs[r * 128 + pc * 8 + (cq & 1) * 4] = b;
    }
}

// ---- mm_chain_mfma: hid = relu(sum_hop h_hop @ W1[hop] + b1), bf16 MFMA ----
// 32 rows x 128 cols per block; 4 waves, wave w covers cols 32w..32w+31.
__global__ __launch_bounds__(256) void mm_chain_mfma(
        const float* __restrict__ h0, const float* __restrict__ h1,
        const float* __restrict__ h2, const float* __restrict__ h3,
        const ushort* __restrict__ W1T,   // [4][128 cols][128 k] bf16
        const float* __restrict__ bias, float* __restrict__ outp) {
    __shared__ ushort hs[32 * 128];
    const int tid = threadIdx.x;
    const int w = tid >> 6;
    const int lane = tid & 63;
    const int lrow = lane & 15;
    const int kgrp = lane >> 4;
    const int row0 = blockIdx.x * 32;

    f32x4 acc[2][2] = {};   // [row-tile][col-tile]

#pragma unroll
    for (int hop = 0; hop < 4; ++hop) {
        const float* hp = (hop == 0) ? h0 : (hop == 1) ? h1 : (hop == 2) ? h2 : h3;
        if (hop) __syncthreads();
        stage_tile_bf16(hs, hp, row0, tid);
        __syncthreads();

#pragma unroll
        for (int kc = 0; kc < 4; ++kc) {
            bf16x8 a[2], b[2];
#pragma unroll
            for (int rt = 0; rt < 2; ++rt) {
                int row = rt * 16 + lrow;
                a[rt] = *(const bf16x8*)&hs[row * 128 + (((kc * 4 + kgrp) ^ (row & 7)) * 8)];
            }
#pragma unroll
            for (int ct = 0; ct < 2; ++ct) {
                int col = w * 32 + ct * 16 + lrow;
                b[ct] = *(const bf16x8*)&W1T[(((size_t)hop * 128 + col) << 7) + kc * 32 + kgrp * 8];
            }
#pragma unroll
            for (int rt = 0; rt < 2; ++rt)
#pragma unroll
                for (int ct = 0; ct < 2; ++ct)
                    acc[rt][ct] = __builtin_amdgcn_mfma_f32_16x16x32_bf16(
                        a[rt], b[ct], acc[rt][ct], 0, 0, 0);
        }
    }

#pragma unroll
    for (int rt = 0; rt < 2; ++rt)
#pragma unroll
        for (int ct = 0; ct < 2; ++ct) {
            int col = w * 32 + ct * 16 + lrow;
            float bv = bias[col];
#pragma unroll
            for (int i = 0; i < 4; ++i) {
                int row = row0 + rt * 16 + kgrp * 4 + i;
                if (row < N_NODES)
                    outp[(size_t)row * 128 + col] = fmaxf(acc[rt][ct][i] + bv, 0.f);
            }
        }
}

// ---- mm_y_mfma: y[hop] = hid @ W2[hop] for all 4 hops; wave w = hop w ----
// 32 rows x (4 hops x 64 cols) per block.
__global__ __launch_bounds__(256) void mm_y_mfma(
        const float* __restrict__ h,
        const ushort* __restrict__ W2T,   // [4][64 cols][128 k] bf16
        float* __restrict__ y) {          // [4][N][64]
    __shared__ ushort hs[32 * 128];
    const int tid = threadIdx.x;
    const int w = tid >> 6;               // = hop
    const int lane = tid & 63;
    const int lrow = lane & 15;
    const int kgrp = lane >> 4;
    const int row0 = blockIdx.x * 32;

    f32x4 acc[2][4] = {};   // [row-tile][col-tile]

    stage_tile_bf16(hs, h, row0, tid);
    __syncthreads();

#pragma unroll
    for (int kc = 0; kc < 4; ++kc) {
        bf16x8 a[2], b[4];
#pragma unroll
        for (int rt = 0; rt < 2; ++rt) {
            int row = rt * 16 + lrow;
            a[rt] = *(const bf16x8*)&hs[row * 128 + (((kc * 4 + kgrp) ^ (row & 7)) * 8)];
        }
#pragma unroll
        for (int ct = 0; ct < 4; ++ct) {
            int col = ct * 16 + lrow;
            b[ct] = *(const bf16x8*)&W2T[(((size_t)w * 64 + col) << 7) + kc * 32 + kgrp * 8];
        }
#pragma unroll
        for (int rt = 0; rt < 2; ++rt)
#pragma unroll
            for (int ct = 0; ct < 4; ++ct)
                acc[rt][ct] = __builtin_amdgcn_mfma_f32_16x16x32_bf16(
                    a[rt], b[ct], acc[rt][ct], 0, 0, 0);
    }

    float* yp = y + (size_t)w * N_NODES * 64;
#pragma unroll
    for (int rt = 0; rt < 2; ++rt)
#pragma unroll
        for (int ct = 0; ct < 4; ++ct) {
            int col = ct * 16 + lrow;
#pragma unroll
            for (int i = 0; i < 4; ++i) {
                int row = row0 + rt * 16 + kgrp * 4 + i;
                if (row < N_NODES)
                    yp[(size_t)row * 64 + col] = acc[rt][ct][i];
            }
        }
}

// ---------------- launch ----------------

extern "C" void kernel_launch(void* const* d_in, const int* in_sizes, int n_in,
                              void* d_out, int out_size, void* d_ws, size_t ws_size,
                              hipStream_t stream) {
    const float* x  = (const float*)d_in[0];
    const int*   ei = (const int*)d_in[1];
    const float* W1 = (const float*)d_in[2];
    const float* b1 = (const float*)d_in[3];
    const float* W2 = (const float*)d_in[4];
    const float* b2 = (const float*)d_in[5];
    float* out = (float*)d_out;

    const int* row = ei;             // edge_index[0]
    const int* col = ei + N_EDGES;   // edge_index[1]

    char* ws_base = (char*)d_ws;
    size_t o = 0;
    auto carve = [&](size_t bytes) {
        void* p = ws_base + o;
        o = (o + bytes + 511) & ~(size_t)511;
        return p;
    };
    int*    deg    = (int*)carve(N_NODES * 4);
    float*  dinv   = (float*)carve(N_NODES * 4);
    int*    off    = (int*)carve((N_NODES + 1) * 4);
    int*    cursor = (int*)carve(N_NODES * 4);
    int*    bsum   = (int*)carve(NB_SCAN * 4);
    int2*   meta   = (int2*)carve((size_t)N_EDGES * 8);
    ushort* W1T    = (ushort*)carve(4 * 128 * 128 * 2);
    ushort* W2T    = (ushort*)carve(4 * 64 * 128 * 2);
    float*  A      = (float*)carve((size_t)N_NODES * 128 * 4);
    float*  B      = (float*)carve((size_t)N_NODES * 128 * 4);
    float*  C      = (float*)carve((size_t)N_NODES * 128 * 4);
    float*  hid    = (float*)carve((size_t)N_NODES * 128 * 4);
    float*  y2     = (float*)carve((size_t)4 * N_NODES * 64 * 4);   // [4][N][64]
    float*  T2     = (float*)carve((size_t)N_NODES * 64 * 4);

    float* y2_0 = y2;
    float* y2_1 = y2 + (size_t)1 * N_NODES * 64;
    float* y2_2 = y2 + (size_t)2 * N_NODES * 64;
    float* y2_3 = y2 + (size_t)3 * N_NODES * 64;
    float* S2   = y2_3;   // reuse once y2_3 is consumed

    const int nb_e = (N_EDGES + 255) / 256;   // 3125

    // W transpose/convert (independent of graph prep -- launch first)
    wtrans<128><<<256, 256, 0, stream>>>(W1, W1T);
    wtrans<64><<<128, 256, 0, stream>>>(W2, W2T);

    // graph preprocessing
    hipMemsetAsync(deg, 0, N_NODES * 4, stream);
    count_deg_kernel<<<nb_e, 256, 0, stream>>>(col, deg, N_EDGES);
    scan1_kernel<<<NB_SCAN, 256, 0, stream>>>(deg, bsum, dinv);
    scan2_kernel<<<1, 256, 0, stream>>>(bsum);
    scan3_kernel<<<NB_SCAN, 256, 0, stream>>>(deg, bsum, off, cursor);
    scatter_csr_kernel<<<nb_e, 256, 0, stream>>>(row, col, dinv, cursor, meta, N_EDGES);

    // ----- layer 1: chain props, then one fused K=512 MFMA matmul -> hid
    prop128<0, false><<<12500, 256, 0, stream>>>(x, off, meta, nullptr, nullptr, A);
    prop128<0, false><<<12500, 256, 0, stream>>>(A, off, meta, nullptr, nullptr, B);
    prop128<0, false><<<12500, 256, 0, stream>>>(B, off, meta, nullptr, nullptr, C);
    mm_chain_mfma<<<1563, 256, 0, stream>>>(x, A, B, C, W1T, b1, hid);

    // ----- layer 2 (Horner): out = log_softmax(z0 + A(z1 + A(z2 + A z3)) + b2)
    mm_y_mfma<<<1563, 256, 0, stream>>>(hid, W2T, y2);
    prop64<0><<<12500, 256, 0, stream>>>(y2_3, off, meta, y2_2, nullptr, T2);
    prop64<0><<<12500, 256, 0, stream>>>(T2,   off, meta, y2_1, nullptr, S2);
    prop64<2><<<12500, 256, 0, stream>>>(S2,   off, meta, y2_0, b2,      out);
}

// Round 10
// 376.794 us; speedup vs baseline: 3.5822x; 1.2701x over previous
//
#include <hip/hip_runtime.h>
#include <math.h>

// TAGCN 2-layer GNN on MI355X.
// R10 = R9 + all intermediate feature arrays in bf16 (fp32 accumulation):
// - x converted once to xb; props gather bf16 rows (prop128: 2 lines/edge,
//   prop64: 1 line/edge), unpack via bit-ops, accumulate fp32, store bf16.
// - mm kernels stage bf16 tiles directly (no conversion), write bf16.
// - final log_softmax output stays fp32.
// R9 measured: props 3.76 TB/s, VALUBusy 7.4% -> pure memory path; halving
// bytes/lines is the matching lever.

#define N_NODES 50000
#define N_EDGES 800000
#define NB_SCAN 196          // ceil(50000/256)

typedef __attribute__((ext_vector_type(8))) short bf16x8;
typedef __attribute__((ext_vector_type(4))) float f32x4;

__device__ inline ushort f2b(float x) {   // fp32 -> bf16 bits, RTNE
    unsigned u = __float_as_uint(x);
    return (ushort)((u + 0x7FFFu + ((u >> 16) & 1u)) >> 16);
}
__device__ inline float b2f(ushort b) { return __uint_as_float(((unsigned)b) << 16); }
__device__ inline float lo_f(unsigned u) { return __uint_as_float(u << 16); }
__device__ inline float hi_f(unsigned u) { return __uint_as_float(u & 0xFFFF0000u); }
__device__ inline unsigned pack2(float lo, float hi) {
    return ((unsigned)f2b(hi) << 16) | (unsigned)f2b(lo);
}

// ---------------- graph preprocessing ----------------

__global__ void count_deg_kernel(const int* __restrict__ col, int* __restrict__ deg, int e) {
    int i = blockIdx.x * 256 + threadIdx.x;
    if (i < e) atomicAdd(&deg[col[i]], 1);
}

__global__ void scan1_kernel(const int* __restrict__ deg, int* __restrict__ bsum,
                             float* __restrict__ dinv) {
    __shared__ int sd[256];
    int tid = threadIdx.x;
    int i = blockIdx.x * 256 + tid;
    int v = (i < N_NODES) ? deg[i] : 0;
    if (i < N_NODES) dinv[i] = (v > 0) ? (1.0f / sqrtf((float)v)) : 0.f;
    sd[tid] = v;
    __syncthreads();
    for (int o = 128; o > 0; o >>= 1) {
        if (tid < o) sd[tid] += sd[tid + o];
        __syncthreads();
    }
    if (tid == 0) bsum[blockIdx.x] = sd[0];
}

__global__ void scan2_kernel(int* __restrict__ bsum) {
    __shared__ int sd[256];
    int tid = threadIdx.x;
    int v = (tid < NB_SCAN) ? bsum[tid] : 0;
    sd[tid] = v;
    __syncthreads();
    for (int o = 1; o < 256; o <<= 1) {
        int t = (tid >= o) ? sd[tid - o] : 0;
        __syncthreads();
        sd[tid] += t;
        __syncthreads();
    }
    if (tid < NB_SCAN) bsum[tid] = sd[tid] - v;   // exclusive
}

__global__ void scan3_kernel(const int* __restrict__ deg, const int* __restrict__ bsum,
                             int* __restrict__ off, int* __restrict__ cursor) {
    __shared__ int sd[256];
    int tid = threadIdx.x;
    int i = blockIdx.x * 256 + tid;
    int v = (i < N_NODES) ? deg[i] : 0;
    sd[tid] = v;
    __syncthreads();
    for (int o = 1; o < 256; o <<= 1) {
        int t = (tid >= o) ? sd[tid - o] : 0;
        __syncthreads();
        sd[tid] += t;
        __syncthreads();
    }
    if (i < N_NODES) {
        int val = bsum[blockIdx.x] + sd[tid] - v;
        off[i] = val;
        cursor[i] = val;
    }
    if (i == N_NODES - 1) off[N_NODES] = N_EDGES;
}

__global__ void scatter_csr_kernel(const int* __restrict__ row, const int* __restrict__ col,
                                   const float* __restrict__ dinv, int* __restrict__ cursor,
                                   int2* __restrict__ meta, int e) {
    int i = blockIdx.x * 256 + threadIdx.x;
    if (i < e) {
        int r = row[i], c = col[i];
        int p = atomicAdd(&cursor[c], 1);
        float w = dinv[r] * dinv[c];
        meta[p] = make_int2(r, __float_as_int(w));
    }
}

// -------- x -> bf16 (once per call) --------
__global__ void cvt_bf16_kernel(const float* __restrict__ src, ushort* __restrict__ dst) {
    int i = blockIdx.x * 256 + threadIdx.x;   // one float4 per thread
    float4 v = ((const float4*)src)[i];
    ushort4 b;
    b.x = f2b(v.x); b.y = f2b(v.y); b.z = f2b(v.z); b.w = f2b(v.w);
    ((ushort4*)dst)[i] = b;
}

// -------- W transpose + bf16 convert: W[4][128][NC] -> WT[4][NC][128] --------
template <int NC>
__global__ void wtrans(const float* __restrict__ W, ushort* __restrict__ WT) {
    int idx = blockIdx.x * 256 + threadIdx.x;   // idx = ((hop*NC + c)*128 + k)
    if (idx < 4 * 128 * NC) {
        int k = idx & 127;
        int hc = idx >> 7;
        int c = hc % NC;
        int hop = hc / NC;
        WT[idx] = f2b(W[((size_t)hop * 128 + k) * NC + c]);
    }
}

// -------- prop128b: bf16 rows (128 wide). 1 node / 64-lane wave, u32 (2 bf16)/lane.
__global__ void prop128b(const ushort* __restrict__ h, const int* __restrict__ off,
                         const int2* __restrict__ meta, ushort* __restrict__ out) {
    int node = blockIdx.x * 4 + (threadIdx.x >> 6);
    int lane = threadIdx.x & 63;
    int s = __builtin_amdgcn_readfirstlane(off[node]);
    int e = __builtin_amdgcn_readfirstlane(off[node + 1]);
    const unsigned* h2 = (const unsigned*)h;   // 64 u32 per row

    float accx[4] = {0.f, 0.f, 0.f, 0.f};
    float accy[4] = {0.f, 0.f, 0.f, 0.f};
    int j = s;
    for (; j + 15 < e; j += 16) {
        int2 m[16];
        unsigned v[16];
#pragma unroll
        for (int u = 0; u < 16; ++u) m[u] = meta[j + u];
#pragma unroll
        for (int u = 0; u < 16; ++u) v[u] = h2[(size_t)m[u].x * 64 + lane];
#pragma unroll
        for (int u = 0; u < 16; ++u) {
            float w = __int_as_float(m[u].y);
            accx[u & 3] += w * lo_f(v[u]);
            accy[u & 3] += w * hi_f(v[u]);
        }
    }
    for (; j + 3 < e; j += 4) {
        int2 m[4];
        unsigned v[4];
#pragma unroll
        for (int u = 0; u < 4; ++u) m[u] = meta[j + u];
#pragma unroll
        for (int u = 0; u < 4; ++u) v[u] = h2[(size_t)m[u].x * 64 + lane];
#pragma unroll
        for (int u = 0; u < 4; ++u) {
            float w = __int_as_float(m[u].y);
            accx[u] += w * lo_f(v[u]);
            accy[u] += w * hi_f(v[u]);
        }
    }
    for (; j < e; ++j) {
        int2 m = meta[j];
        unsigned v = h2[(size_t)m.x * 64 + lane];
        float w = __int_as_float(m.y);
        accx[0] += w * lo_f(v);
        accy[0] += w * hi_f(v);
    }
    float rx = (accx[0] + accx[1]) + (accx[2] + accx[3]);
    float ry = (accy[0] + accy[1]) + (accy[2] + accy[3]);
    ((unsigned*)out)[(size_t)node * 64 + lane] = pack2(rx, ry);
}

// -------- prop64b: bf16 64-wide rows (one cache line!). 1 node/wave, ushort/lane.
template <int EPI>   // 0 = accumulate+store bf16, 2 = +bias, log_softmax -> fp32 out
__global__ void prop64b(const ushort* __restrict__ h, const int* __restrict__ off,
                        const int2* __restrict__ meta, const ushort* __restrict__ yadd,
                        const float* __restrict__ bias, void* __restrict__ outp) {
    int node = blockIdx.x * 4 + (threadIdx.x >> 6);
    int lane = threadIdx.x & 63;
    int s = __builtin_amdgcn_readfirstlane(off[node]);
    int e = __builtin_amdgcn_readfirstlane(off[node + 1]);

    float yv = b2f(yadd[(size_t)node * 64 + lane]);

    float acc[4] = {0.f, 0.f, 0.f, 0.f};
    int j = s;
    for (; j + 15 < e; j += 16) {
        int2 m[16];
        ushort v[16];
#pragma unroll
        for (int u = 0; u < 16; ++u) m[u] = meta[j + u];
#pragma unroll
        for (int u = 0; u < 16; ++u) v[u] = h[(size_t)m[u].x * 64 + lane];
#pragma unroll
        for (int u = 0; u < 16; ++u) acc[u & 3] += __int_as_float(m[u].y) * b2f(v[u]);
    }
    for (; j + 3 < e; j += 4) {
        int2 m[4];
        ushort v[4];
#pragma unroll
        for (int u = 0; u < 4; ++u) m[u] = meta[j + u];
#pragma unroll
        for (int u = 0; u < 4; ++u) v[u] = h[(size_t)m[u].x * 64 + lane];
#pragma unroll
        for (int u = 0; u < 4; ++u) acc[u] += __int_as_float(m[u].y) * b2f(v[u]);
    }
    for (; j < e; ++j) {
        int2 m = meta[j];
        acc[0] += __int_as_float(m.y) * b2f(h[(size_t)m.x * 64 + lane]);
    }
    float v = (acc[0] + acc[1]) + (acc[2] + acc[3]) + yv;
    if (EPI == 0) {
        ((ushort*)outp)[(size_t)node * 64 + lane] = f2b(v);
    } else {
        v += bias[lane];
        float m = v;
        for (int d = 32; d > 0; d >>= 1) m = fmaxf(m, __shfl_xor(m, d));
        float su = expf(v - m);
        for (int d = 32; d > 0; d >>= 1) su += __shfl_xor(su, d);
        ((float*)outp)[(size_t)node * 64 + lane] = (v - m) - logf(su);
    }
}

// ---- stage one 32x128 bf16 tile -> LDS with 16B-chunk XOR swizzle ----
__device__ inline void stage_tile(ushort* hs, const ushort* hp, int row0, int tid) {
    const uint4* srcv = (const uint4*)(hp + (size_t)row0 * 128);
    for (int i = tid; i < 512; i += 256) {   // 32 rows x 16 chunks of 16B
        int r = i >> 4, c = i & 15;
        uint4 v = make_uint4(0, 0, 0, 0);
        if (row0 + r < N_NODES) v = srcv[i];
        int pc = c ^ (r & 7);
        *(uint4*)&hs[r * 128 + pc * 8] = v;
    }
}

// ---- mm_chain_mfma: hid = relu(sum_hop h_hop @ W1[hop] + b1), bf16 MFMA ----
// 32 rows x 128 cols per block; 4 waves, wave w covers cols 32w..32w+31.
__global__ __launch_bounds__(256) void mm_chain_mfma(
        const ushort* __restrict__ h0, const ushort* __restrict__ h1,
        const ushort* __restrict__ h2, const ushort* __restrict__ h3,
        const ushort* __restrict__ W1T,   // [4][128 cols][128 k] bf16
        const float* __restrict__ bias, ushort* __restrict__ outp) {
    __shared__ ushort hs[32 * 128];
    const int tid = threadIdx.x;
    const int w = tid >> 6;
    const int lane = tid & 63;
    const int lrow = lane & 15;
    const int kgrp = lane >> 4;
    const int row0 = blockIdx.x * 32;

    f32x4 acc[2][2] = {};   // [row-tile][col-tile]

#pragma unroll
    for (int hop = 0; hop < 4; ++hop) {
        const ushort* hp = (hop == 0) ? h0 : (hop == 1) ? h1 : (hop == 2) ? h2 : h3;
        if (hop) __syncthreads();
        stage_tile(hs, hp, row0, tid);
        __syncthreads();

#pragma unroll
        for (int kc = 0; kc < 4; ++kc) {
            bf16x8 a[2], b[2];
#pragma unroll
            for (int rt = 0; rt < 2; ++rt) {
                int row = rt * 16 + lrow;
                a[rt] = *(const bf16x8*)&hs[row * 128 + (((kc * 4 + kgrp) ^ (row & 7)) * 8)];
            }
#pragma unroll
            for (int ct = 0; ct < 2; ++ct) {
                int col = w * 32 + ct * 16 + lrow;
                b[ct] = *(const bf16x8*)&W1T[(((size_t)hop * 128 + col) << 7) + kc * 32 + kgrp * 8];
            }
#pragma unroll
            for (int rt = 0; rt < 2; ++rt)
#pragma unroll
                for (int ct = 0; ct < 2; ++ct)
                    acc[rt][ct] = __builtin_amdgcn_mfma_f32_16x16x32_bf16(
                        a[rt], b[ct], acc[rt][ct], 0, 0, 0);
        }
    }

#pragma unroll
    for (int rt = 0; rt < 2; ++rt)
#pragma unroll
        for (int ct = 0; ct < 2; ++ct) {
            int col = w * 32 + ct * 16 + lrow;
            float bv = bias[col];
#pragma unroll
            for (int i = 0; i < 4; ++i) {
                int row = row0 + rt * 16 + kgrp * 4 + i;
                if (row < N_NODES)
                    outp[(size_t)row * 128 + col] = f2b(fmaxf(acc[rt][ct][i] + bv, 0.f));
            }
        }
}

// ---- mm_y_mfma: y[hop] = hid @ W2[hop] for all 4 hops; wave w = hop ----
__global__ __launch_bounds__(256) void mm_y_mfma(
        const ushort* __restrict__ h,
        const ushort* __restrict__ W2T,   // [4][64 cols][128 k] bf16
        ushort* __restrict__ y) {         // [4][N][64] bf16
    __shared__ ushort hs[32 * 128];
    const int tid = threadIdx.x;
    const int w = tid >> 6;               // = hop
    const int lane = tid & 63;
    const int lrow = lane & 15;
    const int kgrp = lane >> 4;
    const int row0 = blockIdx.x * 32;

    f32x4 acc[2][4] = {};   // [row-tile][col-tile]

    stage_tile(hs, h, row0, tid);
    __syncthreads();

#pragma unroll
    for (int kc = 0; kc < 4; ++kc) {
        bf16x8 a[2], b[4];
#pragma unroll
        for (int rt = 0; rt < 2; ++rt) {
            int row = rt * 16 + lrow;
            a[rt] = *(const bf16x8*)&hs[row * 128 + (((kc * 4 + kgrp) ^ (row & 7)) * 8)];
        }
#pragma unroll
        for (int ct = 0; ct < 4; ++ct) {
            int col = ct * 16 + lrow;
            b[ct] = *(const bf16x8*)&W2T[(((size_t)w * 64 + col) << 7) + kc * 32 + kgrp * 8];
        }
#pragma unroll
        for (int rt = 0; rt < 2; ++rt)
#pragma unroll
            for (int ct = 0; ct < 4; ++ct)
                acc[rt][ct] = __builtin_amdgcn_mfma_f32_16x16x32_bf16(
                    a[rt], b[ct], acc[rt][ct], 0, 0, 0);
    }

    ushort* yp = y + (size_t)w * N_NODES * 64;
#pragma unroll
    for (int rt = 0; rt < 2; ++rt)
#pragma unroll
        for (int ct = 0; ct < 4; ++ct) {
            int col = ct * 16 + lrow;
#pragma unroll
            for (int i = 0; i < 4; ++i) {
                int row = row0 + rt * 16 + kgrp * 4 + i;
                if (row < N_NODES)
                    yp[(size_t)row * 64 + col] = f2b(acc[rt][ct][i]);
            }
        }
}

// ---------------- launch ----------------

extern "C" void kernel_launch(void* const* d_in, const int* in_sizes, int n_in,
                              void* d_out, int out_size, void* d_ws, size_t ws_size,
                              hipStream_t stream) {
    const float* x  = (const float*)d_in[0];
    const int*   ei = (const int*)d_in[1];
    const float* W1 = (const float*)d_in[2];
    const float* b1 = (const float*)d_in[3];
    const float* W2 = (const float*)d_in[4];
    const float* b2 = (const float*)d_in[5];
    float* out = (float*)d_out;

    const int* row = ei;             // edge_index[0]
    const int* col = ei + N_EDGES;   // edge_index[1]

    char* ws_base = (char*)d_ws;
    size_t o = 0;
    auto carve = [&](size_t bytes) {
        void* p = ws_base + o;
        o = (o + bytes + 511) & ~(size_t)511;
        return p;
    };
    int*    deg    = (int*)carve(N_NODES * 4);
    float*  dinv   = (float*)carve(N_NODES * 4);
    int*    off    = (int*)carve((N_NODES + 1) * 4);
    int*    cursor = (int*)carve(N_NODES * 4);
    int*    bsum   = (int*)carve(NB_SCAN * 4);
    int2*   meta   = (int2*)carve((size_t)N_EDGES * 8);
    ushort* W1T    = (ushort*)carve(4 * 128 * 128 * 2);
    ushort* W2T    = (ushort*)carve(4 * 64 * 128 * 2);
    ushort* xb     = (ushort*)carve((size_t)N_NODES * 128 * 2);
    ushort* A      = (ushort*)carve((size_t)N_NODES * 128 * 2);
    ushort* B      = (ushort*)carve((size_t)N_NODES * 128 * 2);
    ushort* C      = (ushort*)carve((size_t)N_NODES * 128 * 2);
    ushort* hid    = (ushort*)carve((size_t)N_NODES * 128 * 2);
    ushort* y2     = (ushort*)carve((size_t)4 * N_NODES * 64 * 2);   // [4][N][64]
    ushort* T2     = (ushort*)carve((size_t)N_NODES * 64 * 2);

    ushort* y2_0 = y2;
    ushort* y2_1 = y2 + (size_t)1 * N_NODES * 64;
    ushort* y2_2 = y2 + (size_t)2 * N_NODES * 64;
    ushort* y2_3 = y2 + (size_t)3 * N_NODES * 64;
    ushort* S2   = y2_3;   // reuse once y2_3 is consumed

    const int nb_e = (N_EDGES + 255) / 256;   // 3125

    // weight/feature conversions (independent of graph prep -- launch first)
    wtrans<128><<<256, 256, 0, stream>>>(W1, W1T);
    wtrans<64><<<128, 256, 0, stream>>>(W2, W2T);
    cvt_bf16_kernel<<<6250, 256, 0, stream>>>(x, xb);   // 6.4M elems / 4 per thread

    // graph preprocessing
    hipMemsetAsync(deg, 0, N_NODES * 4, stream);
    count_deg_kernel<<<nb_e, 256, 0, stream>>>(col, deg, N_EDGES);
    scan1_kernel<<<NB_SCAN, 256, 0, stream>>>(deg, bsum, dinv);
    scan2_kernel<<<1, 256, 0, stream>>>(bsum);
    scan3_kernel<<<NB_SCAN, 256, 0, stream>>>(deg, bsum, off, cursor);
    scatter_csr_kernel<<<nb_e, 256, 0, stream>>>(row, col, dinv, cursor, meta, N_EDGES);

    // ----- layer 1: chain props (bf16), then one fused K=512 MFMA matmul -> hid (bf16)
    prop128b<<<12500, 256, 0, stream>>>(xb, off, meta, A);
    prop128b<<<12500, 256, 0, stream>>>(A,  off, meta, B);
    prop128b<<<12500, 256, 0, stream>>>(B,  off, meta, C);
    mm_chain_mfma<<<1563, 256, 0, stream>>>(xb, A, B, C, W1T, b1, hid);

    // ----- layer 2 (Horner): out = log_softmax(z0 + A(z1 + A(z2 + A z3)) + b2)
    mm_y_mfma<<<1563, 256, 0, stream>>>(hid, W2T, y2);
    prop64b<0><<<12500, 256, 0, stream>>>(y2_3, off, meta, y2_2, nullptr, T2);
    prop64b<0><<<12500, 256, 0, stream>>>(T2,   off, meta, y2_1, nullptr, S2);
    prop64b<2><<<12500, 256, 0, stream>>>(S2,   off, meta, y2_0, b2,      out);
}